// Round 11
// baseline (158.421 us; speedup 1.0000x reference)
//
#include <hip/hip_runtime.h>
#include <hip/hip_fp16.h>

// TriMul (outgoing) pipeline, MI355X gfx950.
//  K0: Wimg = pre-swizzled LDS image of [Wp|Wg|Wgate] cols; W1t/s1/s2 fold LN-out
//  K1: LayerNorm(d=64) of z -> h fp16, float4 loads (h aliased into omid)
//  K2: proj GEMM h @ W^T + fast sigmoid -> a_t/b_t (k-slot PRE-SWIZZLED),
//      128 rows/block (2 row-groups share one weight stage), g_out
//  K3: batched einsum C_c = A_c*B_c^T — 128x128 tiles, 4-channels-per-XCD
//      generation mapping (4 MB working set = one L2), 3-buffer BK=32 pipeline,
//      counted vmcnt(4), stage interleaved between MFMA bursts, setprio
//  K4: stats + MFMA (raw mid @ W1) + affine LN correction + gate -> out fp32

typedef _Float16 half_t;
typedef _Float16 f16x4 __attribute__((ext_vector_type(4)));
typedef _Float16 f16x8 __attribute__((ext_vector_type(8)));
typedef float f32x4 __attribute__((ext_vector_type(4)));

#define NSEQ 512
#define HID 128
#define ROWS (NSEQ * NSEQ)   // 262144

#define GLOAD16(src, dst)                                                        \
    __builtin_amdgcn_global_load_lds(                                            \
        (const __attribute__((address_space(1))) void*)(src),                    \
        (__attribute__((address_space(3))) void*)(dst), 16, 0, 0)

__device__ __forceinline__ float fast_sigmoid(float x) {
    float e = __builtin_amdgcn_exp2f(-1.44269504088896f * x);
    return __builtin_amdgcn_rcpf(1.f + e);
}

// ---------------------------------------------------------------- K0: weights
__global__ void k_prep_w(const float* __restrict__ Wp, const float* __restrict__ Wg,
                         const float* __restrict__ Wgate,
                         const float* __restrict__ ln_out_w, const float* __restrict__ ln_out_b,
                         const float* __restrict__ Wout,
                         half_t* __restrict__ Wimg, half_t* __restrict__ W1t,
                         float* __restrict__ s1, float* __restrict__ s2) {
    int bid = blockIdx.x, t = threadIdx.x;
    if (bid < 18) {
        int chunk = bid * 256 + t;               // 4608 = 2 ch x 2304
        int ch = chunk >= 2304;
        int q = chunk - ch * 2304;
        int lr = q >> 3, slot = q & 7;
        int co = slot ^ (lr & 7);
        int grow;
        if (lr < 128)      grow = ch * 128 + lr;               // Wp cols
        else if (lr < 256) grow = 256 + ch * 128 + (lr - 128); // Wg cols
        else               grow = 512 + ch * 32 + (lr - 256);  // Wgate cols
        f16x8 vals;
        #pragma unroll
        for (int j = 0; j < 8; ++j) {
            int l = co * 8 + j;
            float v;
            if (grow < 256)      v = Wp[l * 256 + grow];
            else if (grow < 512) v = Wg[l * 256 + (grow - 256)];
            else                 v = Wgate[l * 64 + (grow - 512)];
            vals[j] = (half_t)v;
        }
        *(f16x8*)(Wimg + (size_t)chunk * 8) = vals;
    } else {
        // W1t[o][c] = ln_out_w[c] * Wout[c][o]   (64 x 128)
        #pragma unroll
        for (int i = 0; i < 32; ++i) {
            int idx = t * 32 + i;                // 8192
            int o = idx >> 7, c = idx & 127;
            W1t[idx] = (half_t)(ln_out_w[c] * Wout[c * 64 + o]);
        }
        if (t < 64) {
            float a1 = 0.f, a2 = 0.f;
            for (int c = 0; c < 128; ++c) {
                float wo = Wout[c * 64 + t];
                a1 += ln_out_w[c] * wo;
                a2 += ln_out_b[c] * wo;
            }
            s1[t] = a1; s2[t] = a2;
        }
    }
}

// ---------------------------------------------------------------- K1: LN(d=64)
__global__ __launch_bounds__(256) void k_ln_in(const float* __restrict__ z,
                                               const float* __restrict__ w,
                                               const float* __restrict__ b,
                                               half_t* __restrict__ h) {
    int t = threadIdx.x;
    int row = blockIdx.x * 16 + (t >> 4);
    int c4 = t & 15;
    f32x4 x = *(const f32x4*)(z + (size_t)row * 64 + c4 * 4);
    float s = x[0] + x[1] + x[2] + x[3];
    float s2 = x[0]*x[0] + x[1]*x[1] + x[2]*x[2] + x[3]*x[3];
    #pragma unroll
    for (int off = 1; off < 16; off <<= 1) {
        s  += __shfl_xor(s,  off, 64);
        s2 += __shfl_xor(s2, off, 64);
    }
    float mu = s * (1.f / 64.f);
    float var = s2 * (1.f / 64.f) - mu * mu;
    float rs = rsqrtf(var + 1e-5f);
    f32x4 wv = *(const f32x4*)(w + c4 * 4);
    f32x4 bv = *(const f32x4*)(b + c4 * 4);
    f16x4 o;
    #pragma unroll
    for (int j = 0; j < 4; ++j)
        o[j] = (half_t)((x[j] - mu) * rs * wv[j] + bv[j]);
    *(f16x4*)(h + (size_t)row * 64 + c4 * 4) = o;
}

// ---------------------------------------------------------------- K2: projections
// grid (2048, 2): x = 128-row block (2 row-groups of 64, one shared W stage),
// y = half (0 -> a + gate[0..31], 1 -> b + gate[32..63]).
// LDS 45312 B -> 3 blocks/CU. a_t/b_t written with BK=32 k-slot swizzle
// (slot S holds logical s = S ^ ((i>>1)&3); i = flat_pos>>9 is constant/block).
__global__ __launch_bounds__(256) void k_proj(const half_t* __restrict__ h,
                                              const half_t* __restrict__ Wimg,
                                              half_t* __restrict__ a_t,
                                              half_t* __restrict__ b_t,
                                              half_t* __restrict__ g_out) {
    __shared__ half_t Wl[288 * 64];        // 36 KB, swizzled rows of 128B (image copy)
    __shared__ half_t pgl[64 * 66];        // 8448 B, [c&63][row] stride 66

    int t = threadIdx.x;
    int ch = blockIdx.y;
    int bx = blockIdx.x;
    int r0 = bx * 128;
    int wid = t >> 6, lane = t & 63;
    int m = lane & 15, g = lane >> 4;

    // stage weights via async DMA (image is pre-swizzled + linear)
    const half_t* wsrc = Wimg + (size_t)ch * 2304 * 8;
    #pragma unroll
    for (int it = 0; it < 9; ++it) {
        int cb = it * 256 + wid * 64;      // wave-uniform chunk base
        GLOAD16(wsrc + (size_t)(cb + lane) * 8, Wl + (size_t)cb * 8);
    }

    // A fragments for both row-groups straight from global (h is L2/L3-hot)
    f16x8 af[2][2];
    #pragma unroll
    for (int rp = 0; rp < 2; ++rp)
        #pragma unroll
        for (int ks = 0; ks < 2; ++ks)
            af[rp][ks] = *(const f16x8*)(h + (size_t)(r0 + rp * 64 + wid * 16 + m) * 64
                                           + ks * 32 + g * 8);

    __syncthreads();   // drains gload_lds (vmcnt 0) + all waves staged

    half_t* dst = (ch == 0) ? a_t : b_t;
    int swz = (bx >> 3) & 3;               // = (i>>1)&3, i = bx>>2

    #pragma unroll
    for (int rp = 0; rp < 2; ++rp) {
        int rbase = r0 + rp * 64;
        // p/g pair tiles in 2 groups of 4; pgl holds 64 channels, flushed per group
        for (int grp = 0; grp < 2; ++grp) {
            #pragma unroll
            for (int pt4 = 0; pt4 < 4; ++pt4) {
                int pt = grp * 4 + pt4;
                f32x4 accp = {0.f, 0.f, 0.f, 0.f}, accg = {0.f, 0.f, 0.f, 0.f};
                #pragma unroll
                for (int ks = 0; ks < 2; ++ks) {
                    int kb = (ks * 32 + g * 8) * 2;
                    int lrp = pt * 16 + m;
                    f16x8 bp = *(const f16x8*)((char*)Wl + lrp * 128 + (kb ^ ((lrp & 7) << 4)));
                    int lrg = 128 + pt * 16 + m;
                    f16x8 bg = *(const f16x8*)((char*)Wl + lrg * 128 + (kb ^ ((lrg & 7) << 4)));
                    accp = __builtin_amdgcn_mfma_f32_16x16x32_f16(af[rp][ks], bp, accp, 0, 0, 0);
                    accg = __builtin_amdgcn_mfma_f32_16x16x32_f16(af[rp][ks], bg, accg, 0, 0, 0);
                }
                f16x4 pk;
                #pragma unroll
                for (int r = 0; r < 4; ++r)
                    pk[r] = (half_t)(accp[r] * fast_sigmoid(accg[r]));
                *(f16x4*)&pgl[(pt4 * 16 + m) * 66 + wid * 16 + g * 4] = pk;
            }
            __syncthreads();
            // flush 64 channels x 64 rows; k-slot swizzled for K3's BK=32 LDS image
            #pragma unroll
            for (int it = 0; it < 2; ++it) {
                int chunk = it * 256 + t;      // 512
                int cl = chunk >> 3, r8 = chunk & 7;
                f16x8 v = *(const f16x8*)&pgl[cl * 66 + r8 * 8];
                int dk = (r8 & 4) | ((r8 & 3) ^ swz);
                *(f16x8*)(dst + (size_t)(grp * 64 + cl) * ROWS + rbase + dk * 8) = v;
            }
            __syncthreads();
        }

        // gate tiles -> g_out[row][och] = sigmoid(h @ Wgate)
        #pragma unroll
        for (int gt = 0; gt < 2; ++gt) {
            f32x4 acc = {0.f, 0.f, 0.f, 0.f};
            #pragma unroll
            for (int ks = 0; ks < 2; ++ks) {
                int kb = (ks * 32 + g * 8) * 2;
                int lr = 256 + gt * 16 + m;
                f16x8 bb = *(const f16x8*)((char*)Wl + lr * 128 + (kb ^ ((lr & 7) << 4)));
                acc = __builtin_amdgcn_mfma_f32_16x16x32_f16(af[rp][ks], bb, acc, 0, 0, 0);
            }
            int och = ch * 32 + gt * 16 + m;
            #pragma unroll
            for (int r = 0; r < 4; ++r) {
                float og = fast_sigmoid(acc[r]);
                int grow = rbase + wid * 16 + g * 4 + r;
                g_out[(size_t)grow * 64 + och] = (half_t)og;
            }
        }
    }
}

// ---------------------------------------------------------------- K3: batched einsum
// 2048 blocks x 256 threads (4 waves), 128x128 tile per block, 3 blocks/CU.
// Generation mapping: each XCD's concurrent blocks cover 4 channels x 16 tiles
// -> 4 MB working set = one L2 (panel re-reads become L2 hits).
// 3 K-tile buffers (BK=32, 16 KB each), 2-step prefetch, counted vmcnt(4),
// stage loads interleaved between MFMA bursts. LDS read XOR: slot = g^((row>>1)&3).
#define EBUF 8192   // halves per buffer: A[128x32] at 0, B[128x32] at 4096
__global__ __launch_bounds__(256) void k_einsum(const half_t* __restrict__ a_t,
                                                const half_t* __restrict__ b_t,
                                                half_t* __restrict__ out_mid) {
    __shared__ half_t lds[3 * EBUF];   // 48 KB

    int t = threadIdx.x;
    int wid = t >> 6, lane = t & 63;
    int m = lane & 15, g = lane >> 4;

    int bid = blockIdx.x;
    int xcd = bid & 7;
    int rest = bid >> 3;                 // 0..255
    int gen = rest >> 6;                 // 0..3 (temporal generations)
    int local = rest & 63;
    int c = xcd + 8 * (gen * 4 + (local >> 4));   // 4 channels per XCD per gen
    int tile = local & 15;
    int i0 = (tile >> 2) * 128, j0 = (tile & 3) * 128;

    const half_t* A = a_t + (size_t)c * ROWS;   // [i][k], k-slots pre-swizzled
    const half_t* B = b_t + (size_t)c * ROWS;   // [j][k]
    int wr = wid >> 1, wc = wid & 1;            // 2x2 waves, 64x64 each

    f32x4 acc[4][4] = {};

    // per K-step per thread: A 2 loads (128x32), B 2 loads -> vmcnt quantum 4
#define STAGE_A(ktt, base, it)                                                    \
    {                                                                             \
        int cb = (it) * 256 + wid * 64;      /* wave-uniform chunk base */        \
        int chunk = cb + lane;                                                    \
        GLOAD16(A + (size_t)(i0 + (chunk >> 2)) * 512 + (ktt) * 32 + (chunk & 3) * 8, \
                (base) + (size_t)cb * 8);                                         \
    }
#define STAGE_B(ktt, base, it)                                                    \
    {                                                                             \
        int cb = (it) * 256 + wid * 64;                                           \
        int chunk = cb + lane;                                                    \
        GLOAD16(B + (size_t)(j0 + (chunk >> 2)) * 512 + (ktt) * 32 + (chunk & 3) * 8, \
                (base) + 4096 + (size_t)cb * 8);                                  \
    }
#define STAGE_ALL(ktt, base)                                                      \
    STAGE_A(ktt, base, 0) STAGE_A(ktt, base, 1) STAGE_B(ktt, base, 0) STAGE_B(ktt, base, 1)

    STAGE_ALL(0, lds)
    STAGE_ALL(1, lds + EBUF)

    #pragma unroll
    for (int kt = 0; kt < 16; ++kt) {
        const half_t* Ac = lds + (kt % 3) * EBUF;
        const half_t* Bc = Ac + 4096;
        half_t* nxt = lds + ((kt + 2) % 3) * EBUF;

        // K(t) resident; K(t+1)'s 4 loads may remain in flight
        if (kt <= 14) asm volatile("s_waitcnt vmcnt(4)" ::: "memory");
        else          asm volatile("s_waitcnt vmcnt(0)" ::: "memory");
        __builtin_amdgcn_s_barrier();            // all waves' K(t) landed; buf (t+2)%3 free
        __builtin_amdgcn_sched_barrier(0);

        f16x8 bf[4];
        #pragma unroll
        for (int ni = 0; ni < 4; ++ni) {
            int lrow = wc * 64 + ni * 16 + m;
            bf[ni] = *(const f16x8*)((const char*)Bc + lrow * 64 +
                                     ((g ^ ((lrow >> 1) & 3)) << 4));
        }
        #pragma unroll
        for (int mi = 0; mi < 4; ++mi) {
            int lrow = wr * 64 + mi * 16 + m;
            f16x8 afr = *(const f16x8*)((const char*)Ac + lrow * 64 +
                                        ((g ^ ((lrow >> 1) & 3)) << 4));
            if (kt < 14) {                       // interleave next+2 stage issues
                if (mi == 0)      STAGE_A(kt + 2, nxt, 0)
                else if (mi == 1) STAGE_A(kt + 2, nxt, 1)
                else if (mi == 2) STAGE_B(kt + 2, nxt, 0)
                else              STAGE_B(kt + 2, nxt, 1)
            }
            __builtin_amdgcn_s_setprio(1);
            #pragma unroll
            for (int ni = 0; ni < 4; ++ni)
                acc[mi][ni] = __builtin_amdgcn_mfma_f32_16x16x32_f16(afr, bf[ni], acc[mi][ni], 0, 0, 0);
            __builtin_amdgcn_s_setprio(0);
        }
    }
#undef STAGE_ALL
#undef STAGE_B
#undef STAGE_A

    half_t* O = out_mid + (size_t)c * ROWS;   // [i*512 + j]
    #pragma unroll
    for (int mi = 0; mi < 4; ++mi) {
        #pragma unroll
        for (int ni = 0; ni < 4; ++ni) {
            int row = i0 + wr * 64 + mi * 16 + g * 4;
            int col = j0 + wc * 64 + ni * 16 + m;
            #pragma unroll
            for (int r2 = 0; r2 < 4; ++r2)
                O[(size_t)(row + r2) * 512 + col] = (half_t)acc[mi][ni][r2];
        }
    }
}

// ---------------------------------------------------------------- K4: folded LN + MFMA + gate
// out[p,o] = (rs_p*(x@W1)[o] - mu_p*rs_p*s1[o] + s2[o]) * gate[p,o]
__global__ __launch_bounds__(256) void k_final(const half_t* __restrict__ out_mid,
                                               const half_t* __restrict__ W1t,
                                               const float* __restrict__ s1g,
                                               const float* __restrict__ s2g,
                                               const half_t* __restrict__ g_out,
                                               float* __restrict__ out) {
    __shared__ half_t midl[128 * 64];   // [c][p] 16 KB linear
    __shared__ half_t midt[64 * 128];   // [p][c] 16 KB swizzled
    __shared__ half_t w1l[64 * 128];    // [o][c] 16 KB swizzled
    __shared__ half_t gl[64 * 72];      // [p][o] 9 KB padded
    __shared__ float smu[64], srs[64], s1l[64], s2l[64];

    int t = threadIdx.x;
    int pos0 = blockIdx.x * 64;

    #pragma unroll
    for (int it = 0; it < 4; ++it) {
        int chunk = it * 256 + t;       // 1024
        int cc = chunk >> 3, co = chunk & 7;
        *(uint4*)((char*)midl + cc * 128 + co * 16) =
            *(const uint4*)(out_mid + (size_t)cc * ROWS + pos0 + co * 8);
    }
    // w1l: 64 rows x 16 slots of 16B = 1024 chunks
    #pragma unroll
    for (int it = 0; it < 4; ++it) {
        int chunk = it * 256 + t;       // 1024
        int row = chunk >> 4, slot = chunk & 15;
        *(uint4*)((char*)w1l + row * 256 + ((slot * 16) ^ ((row & 7) << 4))) =
            *(const uint4*)(W1t + row * 128 + slot * 8);
    }
    #pragma unroll
    for (int it = 0; it < 2; ++it) {
        int chunk = it * 256 + t;       // 512
        int row = chunk >> 3, co = chunk & 7;
        *(uint4*)((char*)gl + row * 144 + co * 16) =
            *(const uint4*)(g_out + (size_t)(pos0 + row) * 64 + co * 8);
    }
    if (t < 64) { s1l[t] = s1g[t]; s2l[t] = s2g[t]; }
    __syncthreads();

    // transpose midl -> midt (swizzled) + per-position stats
    {
        int p = t >> 2, q = t & 3;
        float s = 0.f, s2 = 0.f;
        #pragma unroll
        for (int cc4 = 0; cc4 < 4; ++cc4) {
            f16x8 pack;
            #pragma unroll
            for (int j = 0; j < 8; ++j) {
                half_t hv = midl[(q * 32 + cc4 * 8 + j) * 64 + p];
                float v = (float)hv;
                s += v; s2 += v * v;
                pack[j] = hv;
            }
            int slot = q * 4 + cc4;
            *(f16x8*)((char*)midt + p * 256 + ((slot * 16) ^ ((p & 7) << 4))) = pack;
        }
        s  += __shfl_xor(s, 1, 64);  s  += __shfl_xor(s, 2, 64);
        s2 += __shfl_xor(s2, 1, 64); s2 += __shfl_xor(s2, 2, 64);
        if (q == 0) {
            float mu = s * (1.f / 128.f);
            float var = s2 * (1.f / 128.f) - mu * mu;
            smu[p] = mu;
            srs[p] = rsqrtf(var + 1e-5f);
        }
    }
    __syncthreads();

    int wid = t >> 6, lane = t & 63;
    int m = lane & 15, g = lane >> 4;

    f32x4 acc[4] = {};
    #pragma unroll
    for (int ks = 0; ks < 4; ++ks) {
        int arow = wid * 16 + m;
        f16x8 af = *(const f16x8*)((char*)midt + arow * 256 +
                                   (((4 * ks + g) * 16) ^ ((arow & 7) << 4)));
        #pragma unroll
        for (int ni = 0; ni < 4; ++ni) {
            int brow = ni * 16 + m;
            f16x8 bf = *(const f16x8*)((char*)w1l + brow * 256 +
                                       (((4 * ks + g) * 16) ^ ((brow & 7) << 4)));
            acc[ni] = __builtin_amdgcn_mfma_f32_16x16x32_f16(af, bf, acc[ni], 0, 0, 0);
        }
    }

    #pragma unroll
    for (int ni = 0; ni < 4; ++ni) {
        int o = ni * 16 + m;
        float v1 = s1l[o], v2 = s2l[o];
        #pragma unroll
        for (int r = 0; r < 4; ++r) {
            int lrow = wid * 16 + g * 4 + r;
            float mu = smu[lrow], rs = srs[lrow];
            float val = acc[ni][r] * rs - mu * rs * v1 + v2;
            float gate = (float)gl[lrow * 72 + o];
            out[(size_t)(pos0 + lrow) * 64 + o] = val * gate;
        }
    }
}

// ---------------------------------------------------------------- launch
extern "C" void kernel_launch(void* const* d_in, const int* in_sizes, int n_in,
                              void* d_out, int out_size, void* d_ws, size_t ws_size,
                              hipStream_t stream) {
    const float* z        = (const float*)d_in[0];
    const float* ln_in_w  = (const float*)d_in[1];
    const float* ln_in_b  = (const float*)d_in[2];
    const float* Wp       = (const float*)d_in[3];
    const float* Wg       = (const float*)d_in[4];
    const float* ln_out_w = (const float*)d_in[5];
    const float* ln_out_b = (const float*)d_in[6];
    const float* Wout     = (const float*)d_in[7];
    const float* Wgate    = (const float*)d_in[8];
    float* out = (float*)d_out;

    // ws layout (235,012,096 B total < 256 MiB):
    //   [0, 128K)    Wimg(73728) | W1t@81920(16384) | s1@98304(256) | s2@98560(256)
    //   [128K,+67MB) a_t ; +67MB b_t ; +33.5MB gout ; +67MB omid (h aliases omid)
    char* wsb = (char*)d_ws;
    half_t* Wimg = (half_t*)wsb;
    half_t* W1t  = (half_t*)(wsb + 81920);
    float*  s1   = (float*)(wsb + 98304);
    float*  s2   = (float*)(wsb + 98560);
    half_t* a_t  = (half_t*)(wsb + 131072);
    half_t* b_t  = a_t + (size_t)HID * ROWS;
    half_t* gout = b_t + (size_t)HID * ROWS;
    half_t* omid = gout + (size_t)ROWS * 64;
    half_t* h    = omid;   // aliased: h consumed by K2, omid produced by K3

    k_prep_w<<<dim3(19), dim3(256), 0, stream>>>(Wp, Wg, Wgate, ln_out_w, ln_out_b, Wout,
                                                 Wimg, W1t, s1, s2);
    k_ln_in<<<dim3(ROWS / 16), dim3(256), 0, stream>>>(z, ln_in_w, ln_in_b, h);
    k_proj<<<dim3(ROWS / 128, 2), dim3(256), 0, stream>>>(h, Wimg, a_t, b_t, gout);
    k_einsum<<<dim3(2048), dim3(256), 0, stream>>>(a_t, b_t, omid);
    k_final<<<dim3(ROWS / 64), dim3(256), 0, stream>>>(omid, W1t, s1, s2, gout, out);
}